// Round 8
// baseline (275.217 us; speedup 1.0000x reference)
//
#include <hip/hip_runtime.h>

#define N_NODES 100000
#define N_EDGES 1600000
#define D_FEAT 64

#define N_PART 8
#define SLICE  (N_EDGES / N_PART)          // 200000, exact

#define RB_LOG 7
#define ROWS_PER_BUCKET 128
#define N_BUCKET ((N_NODES + ROWS_PER_BUCKET - 1) / ROWS_PER_BUCKET)  // 782
#define N_CELL (N_BUCKET * N_PART)         // 6256

#define COL_BITS 17
#define COL_MASK ((1 << COL_BITS) - 1)

#define MAXREC 3072
#define PAD 16   // one contended counter per 64B line

__device__ __forceinline__ int   ntload_i(const int* p)   { return __builtin_nontemporal_load(p); }
__device__ __forceinline__ float ntload_f(const float* p) { return __builtin_nontemporal_load(p); }

// -------- phase A+B fused: 2D histogram + last-block inline scan -----------
__global__ __launch_bounds__(256) void hist_scan_kernel(
    const int* __restrict__ rows, int* __restrict__ histG,
    int* __restrict__ done, int* __restrict__ cellptr, int* __restrict__ cursor)
{
    __shared__ int h[N_BUCKET];
    for (int i = threadIdx.x; i < N_BUCKET; i += 256) h[i] = 0;
    __syncthreads();

    int part = blockIdx.x & (N_PART - 1);
    int blk  = blockIdx.x >> 3;
    int nblk = gridDim.x >> 3;
    int base = part * SLICE;

    for (int e = blk * 256 + threadIdx.x; e < SLICE; e += nblk * 256)
        atomicAdd(&h[ntload_i(rows + base + e) >> RB_LOG], 1);
    __syncthreads();

    for (int i = threadIdx.x; i < N_BUCKET; i += 256)
        if (h[i]) atomicAdd(&histG[(part * N_BUCKET + i) * PAD], h[i]);

    // signal completion; last block performs the scan inline
    __threadfence();
    __shared__ int isLast;
    if (threadIdx.x == 0)
        isLast = (atomicAdd(done, 1) == (int)gridDim.x - 1);
    __syncthreads();
    if (!isLast) return;
    __threadfence();

    const int per = (N_CELL + 255) / 256;   // 25 cells per thread
    __shared__ int ssum[2][256];
    int t = threadIdx.x;

    int sum = 0;
    for (int j = 0; j < per; ++j) {
        int cm = t * per + j;
        if (cm < N_CELL) {
            int p = cm & (N_PART - 1), b = cm >> 3;
            sum += __hip_atomic_load(&histG[(p * N_BUCKET + b) * PAD],
                                     __ATOMIC_RELAXED, __HIP_MEMORY_SCOPE_AGENT);
        }
    }
    ssum[0][t] = sum;
    __syncthreads();
    int src = 0;
    for (int off = 1; off < 256; off <<= 1) {
        int x = ssum[src][t];
        if (t >= off) x += ssum[src][t - off];
        ssum[1 - src][t] = x;
        __syncthreads();
        src ^= 1;
    }
    int run = ssum[src][t] - sum;   // exclusive prefix across threads
    for (int j = 0; j < per; ++j) {
        int cm = t * per + j;
        if (cm < N_CELL) {
            int p = cm & (N_PART - 1), b = cm >> 3;
            int x = __hip_atomic_load(&histG[(p * N_BUCKET + b) * PAD],
                                      __ATOMIC_RELAXED, __HIP_MEMORY_SCOPE_AGENT);
            cellptr[cm] = run;
            cursor[(p * N_BUCKET + b) * PAD] = run;
            run += x;
        }
    }
    if (t == 0) cellptr[N_CELL] = N_EDGES;
}

// ---------------- phase C: append edges into (part,bucket) cells -----------
__global__ __launch_bounds__(256) void scatter_kernel(
    const float* __restrict__ vals, const int* __restrict__ rows,
    const int* __restrict__ cols, int* __restrict__ cursor,
    int2* __restrict__ rec)
{
    int part = blockIdx.x & (N_PART - 1);
    int blk  = blockIdx.x >> 3;
    int nblk = gridDim.x >> 3;
    int base = part * SLICE;
    int* cur = cursor + part * N_BUCKET * PAD;

    for (int e = blk * 256 + threadIdx.x; e < SLICE; e += nblk * 256) {
        int idx = base + e;
        int r = ntload_i(rows + idx);
        int c = ntload_i(cols + idx);
        float v = ntload_f(vals + idx);
        int b = r >> RB_LOG;
        int pos = atomicAdd(&cur[b * PAD], 1);
        int packed = ((r & (ROWS_PER_BUCKET - 1)) << COL_BITS) | c;
        rec[pos] = make_int2(packed, __float_as_int(v));
    }
}

// ---- phase D: per-half-bucket LDS index-sort + register gather ------------
// 2 blocks per bucket; each handles 8 of 16 feature chunks (32 features).
__global__ __launch_bounds__(256) void gather_kernel(
    const float* __restrict__ H, const int2* __restrict__ rec,
    const int* __restrict__ cellptr, float* __restrict__ out)
{
    __shared__ int2           recbuf[MAXREC];
    __shared__ unsigned short order[MAXREC];
    __shared__ int            rstart[ROWS_PER_BUCKET + 1];
    __shared__ int            rcur[ROWS_PER_BUCKET];
    __shared__ int            sbuf[2][ROWS_PER_BUCKET];

    int b    = blockIdx.x >> 1;
    int half = blockIdx.x & 1;
    int start = cellptr[b * N_PART];
    int end   = cellptr[b * N_PART + N_PART];

    int tid = threadIdx.x;
    int rg = tid >> 3;                 // row group 0..31 (4 rows each)
    int fc = (tid & 7) + half * 8;     // global feature chunk 0..15
    const float4* H4 = reinterpret_cast<const float4*>(H);

    float4 acc[4];
    #pragma unroll
    for (int k = 0; k < 4; ++k) acc[k] = make_float4(0.f, 0.f, 0.f, 0.f);

    for (int base = start; base < end; base += MAXREC) {
        int n = min(end - base, MAXREC);

        if (tid < ROWS_PER_BUCKET) rcur[tid] = 0;
        __syncthreads();

        for (int i = tid; i < n; i += 256) {
            long long rv = __builtin_nontemporal_load(
                reinterpret_cast<const long long*>(rec + base + i));
            int2 r;
            r.x = (int)(rv & 0xffffffffLL);
            r.y = (int)(rv >> 32);
            recbuf[i] = r;
            atomicAdd(&rcur[r.x >> COL_BITS], 1);
        }
        __syncthreads();

        if (tid < ROWS_PER_BUCKET) sbuf[0][tid] = rcur[tid];
        __syncthreads();
        int src = 0;
        for (int off = 1; off < ROWS_PER_BUCKET; off <<= 1) {
            if (tid < ROWS_PER_BUCKET) {
                int x = sbuf[src][tid];
                if (tid >= off) x += sbuf[src][tid - off];
                sbuf[1 - src][tid] = x;
            }
            __syncthreads();
            src ^= 1;
        }
        if (tid < ROWS_PER_BUCKET) rstart[tid + 1] = sbuf[src][tid];
        if (tid == 0) rstart[0] = 0;
        __syncthreads();
        if (tid < ROWS_PER_BUCKET) rcur[tid] = rstart[tid];
        __syncthreads();

        for (int i = tid; i < n; i += 256) {
            int ro = recbuf[i].x >> COL_BITS;
            int pos = atomicAdd(&rcur[ro], 1);
            order[pos] = (unsigned short)i;
        }
        __syncthreads();

        #pragma unroll
        for (int k = 0; k < 4; ++k) {
            int ro = k * 32 + rg;
            int s = rstart[ro], e2 = rstart[ro + 1];
            int i = s;
            for (; i + 4 <= e2; i += 4) {
                int j0 = order[i], j1 = order[i + 1];
                int j2 = order[i + 2], j3 = order[i + 3];
                int2 r0 = recbuf[j0];
                int2 r1 = recbuf[j1];
                int2 r2 = recbuf[j2];
                int2 r3 = recbuf[j3];
                float4 h0 = H4[(r0.x & COL_MASK) * 16 + fc];
                float4 h1 = H4[(r1.x & COL_MASK) * 16 + fc];
                float4 h2 = H4[(r2.x & COL_MASK) * 16 + fc];
                float4 h3 = H4[(r3.x & COL_MASK) * 16 + fc];
                float v0 = __int_as_float(r0.y);
                float v1 = __int_as_float(r1.y);
                float v2 = __int_as_float(r2.y);
                float v3 = __int_as_float(r3.y);
                acc[k].x += v0 * h0.x; acc[k].y += v0 * h0.y;
                acc[k].z += v0 * h0.z; acc[k].w += v0 * h0.w;
                acc[k].x += v1 * h1.x; acc[k].y += v1 * h1.y;
                acc[k].z += v1 * h1.z; acc[k].w += v1 * h1.w;
                acc[k].x += v2 * h2.x; acc[k].y += v2 * h2.y;
                acc[k].z += v2 * h2.z; acc[k].w += v2 * h2.w;
                acc[k].x += v3 * h3.x; acc[k].y += v3 * h3.y;
                acc[k].z += v3 * h3.z; acc[k].w += v3 * h3.w;
            }
            for (; i < e2; ++i) {
                int j0 = order[i];
                int2 r0 = recbuf[j0];
                float4 h0 = H4[(r0.x & COL_MASK) * 16 + fc];
                float v0 = __int_as_float(r0.y);
                acc[k].x += v0 * h0.x; acc[k].y += v0 * h0.y;
                acc[k].z += v0 * h0.z; acc[k].w += v0 * h0.w;
            }
        }
        __syncthreads();
    }

    int rowbase = b * ROWS_PER_BUCKET;
    #pragma unroll
    for (int k = 0; k < 4; ++k) {
        int row = rowbase + k * 32 + rg;
        if (row < N_NODES)
            reinterpret_cast<float4*>(out)[row * 16 + fc] = acc[k];
    }
}

extern "C" void kernel_launch(void* const* d_in, const int* in_sizes, int n_in,
                              void* d_out, int out_size, void* d_ws, size_t ws_size,
                              hipStream_t stream) {
    const float* H    = (const float*)d_in[0];
    const float* vals = (const float*)d_in[1];
    const int*   rows = (const int*)d_in[2];
    const int*   cols = (const int*)d_in[3];
    float* out = (float*)d_out;

    char* ws = (char*)d_ws;
    int2* rec     = (int2*)ws;                       // E * 8B = 12.8 MB
    int*  histG   = (int*)(rec + N_EDGES);           // N_CELL*PAD
    int*  done    = histG + N_CELL * PAD;            // 16 ints
    int*  cursor  = done + 16;                       // N_CELL*PAD
    int*  cellptr = cursor + N_CELL * PAD;           // N_CELL+1

    // zero histG + done in one memset
    hipMemsetAsync(histG, 0, (N_CELL * PAD + 16) * sizeof(int), stream);

    hist_scan_kernel<<<512, 256, 0, stream>>>(rows, histG, done, cellptr, cursor);
    scatter_kernel<<<2048, 256, 0, stream>>>(vals, rows, cols, cursor, rec);
    gather_kernel<<<N_BUCKET * 2, 256, 0, stream>>>(H, rec, cellptr, out);
}

// Round 9
// 229.696 us; speedup vs baseline: 1.1982x; 1.1982x over previous
//
#include <hip/hip_runtime.h>

#define N_NODES 100000
#define N_EDGES 1600000
#define D_FEAT 64

#define N_PART 8
#define SLICE  (N_EDGES / N_PART)          // 200000, exact

#define RB_LOG 7
#define ROWS_PER_BUCKET 128
#define N_BUCKET ((N_NODES + ROWS_PER_BUCKET - 1) / ROWS_PER_BUCKET)  // 782
#define N_CELL (N_BUCKET * N_PART)         // 6256

#define COL_BITS 17
#define COL_MASK ((1 << COL_BITS) - 1)

#define CAP 512        // slots per (bucket,part) cell; mean 256, 16-sigma margin
#define MAXREC 3072
#define PAD 16         // one contended counter per 64B line
#define OVF_MAX 4096

__device__ __forceinline__ int   ntload_i(const int* p)   { return __builtin_nontemporal_load(p); }
__device__ __forceinline__ float ntload_f(const float* p) { return __builtin_nontemporal_load(p); }

// ------- scatter: append edges into fixed-capacity (bucket,part) cells -----
// cell = b*8 + part; records at rec[cell*CAP + pos]. No histogram/scan pass.
__global__ __launch_bounds__(256) void scatter_kernel(
    const float* __restrict__ vals, const int* __restrict__ rows,
    const int* __restrict__ cols, int* __restrict__ cursor,
    int2* __restrict__ rec, int4* __restrict__ ovf, int* __restrict__ ovf_cnt)
{
    int part = blockIdx.x & (N_PART - 1);
    int blk  = blockIdx.x >> 3;
    int nblk = gridDim.x >> 3;
    int base = part * SLICE;

    for (int e = blk * 256 + threadIdx.x; e < SLICE; e += nblk * 256) {
        int idx = base + e;
        int r = ntload_i(rows + idx);
        int c = ntload_i(cols + idx);
        float v = ntload_f(vals + idx);
        int b = r >> RB_LOG;
        int cell = b * N_PART + part;
        int pos = atomicAdd(&cursor[cell * PAD], 1);
        if (pos < CAP) {
            int packed = ((r & (ROWS_PER_BUCKET - 1)) << COL_BITS) | c;
            rec[cell * CAP + pos] = make_int2(packed, __float_as_int(v));
        } else {
            int opos = atomicAdd(ovf_cnt, 1);
            if (opos < OVF_MAX)
                ovf[opos] = make_int4(r, c, __float_as_int(v), 0);
        }
    }
}

// ---- gather: per-bucket LDS index-sort + register accumulate --------------
__global__ __launch_bounds__(256) void gather_kernel(
    const float* __restrict__ H, const int2* __restrict__ rec,
    const int* __restrict__ cursor, const int4* __restrict__ ovf,
    const int* __restrict__ ovf_cnt, float* __restrict__ out)
{
    __shared__ int2           recbuf[MAXREC];
    __shared__ unsigned short order[MAXREC];
    __shared__ int            rstart[ROWS_PER_BUCKET + 1];
    __shared__ int            rcur[ROWS_PER_BUCKET];
    __shared__ int            sbuf[2][ROWS_PER_BUCKET];

    int b = blockIdx.x;
    int tid = threadIdx.x;
    int rg = tid >> 4;
    int fc = tid & 15;
    const float4* H4 = reinterpret_cast<const float4*>(H);

    float4 acc[8];
    #pragma unroll
    for (int k = 0; k < 8; ++k) acc[k] = make_float4(0.f, 0.f, 0.f, 0.f);

    int p = 0;
    while (p < N_PART) {
        // ---- fill recbuf from as many cells as fit; histogram rows ----
        if (tid < ROWS_PER_BUCKET) rcur[tid] = 0;
        __syncthreads();

        int n = 0;
        while (p < N_PART) {
            int cell = b * N_PART + p;
            int cnt = min(cursor[cell * PAD], CAP);
            if (n + cnt > MAXREC) break;
            const int2* src = rec + cell * CAP;
            for (int i = tid; i < cnt; i += 256) {
                int2 r = src[i];
                recbuf[n + i] = r;
                atomicAdd(&rcur[r.x >> COL_BITS], 1);
            }
            n += cnt;
            ++p;
        }
        __syncthreads();

        // ---- scan 128 counts -> rstart ----
        if (tid < ROWS_PER_BUCKET) sbuf[0][tid] = rcur[tid];
        __syncthreads();
        int src = 0;
        for (int off = 1; off < ROWS_PER_BUCKET; off <<= 1) {
            if (tid < ROWS_PER_BUCKET) {
                int x = sbuf[src][tid];
                if (tid >= off) x += sbuf[src][tid - off];
                sbuf[1 - src][tid] = x;
            }
            __syncthreads();
            src ^= 1;
        }
        if (tid < ROWS_PER_BUCKET) rstart[tid + 1] = sbuf[src][tid];
        if (tid == 0) rstart[0] = 0;
        __syncthreads();
        if (tid < ROWS_PER_BUCKET) rcur[tid] = rstart[tid];
        __syncthreads();

        // ---- index-sort by row ----
        for (int i = tid; i < n; i += 256) {
            int ro = recbuf[i].x >> COL_BITS;
            int pos = atomicAdd(&rcur[ro], 1);
            order[pos] = (unsigned short)i;
        }
        __syncthreads();

        // ---- register-accumulate gather ----
        #pragma unroll
        for (int k = 0; k < 8; ++k) {
            int ro = k * 16 + rg;
            int s = rstart[ro], e2 = rstart[ro + 1];
            int i = s;
            for (; i + 4 <= e2; i += 4) {
                int j0 = order[i], j1 = order[i + 1];
                int j2 = order[i + 2], j3 = order[i + 3];
                int2 r0 = recbuf[j0];
                int2 r1 = recbuf[j1];
                int2 r2 = recbuf[j2];
                int2 r3 = recbuf[j3];
                float4 h0 = H4[(r0.x & COL_MASK) * 16 + fc];
                float4 h1 = H4[(r1.x & COL_MASK) * 16 + fc];
                float4 h2 = H4[(r2.x & COL_MASK) * 16 + fc];
                float4 h3 = H4[(r3.x & COL_MASK) * 16 + fc];
                float v0 = __int_as_float(r0.y);
                float v1 = __int_as_float(r1.y);
                float v2 = __int_as_float(r2.y);
                float v3 = __int_as_float(r3.y);
                acc[k].x += v0 * h0.x; acc[k].y += v0 * h0.y;
                acc[k].z += v0 * h0.z; acc[k].w += v0 * h0.w;
                acc[k].x += v1 * h1.x; acc[k].y += v1 * h1.y;
                acc[k].z += v1 * h1.z; acc[k].w += v1 * h1.w;
                acc[k].x += v2 * h2.x; acc[k].y += v2 * h2.y;
                acc[k].z += v2 * h2.z; acc[k].w += v2 * h2.w;
                acc[k].x += v3 * h3.x; acc[k].y += v3 * h3.y;
                acc[k].z += v3 * h3.z; acc[k].w += v3 * h3.w;
            }
            for (; i < e2; ++i) {
                int j0 = order[i];
                int2 r0 = recbuf[j0];
                float4 h0 = H4[(r0.x & COL_MASK) * 16 + fc];
                float v0 = __int_as_float(r0.y);
                acc[k].x += v0 * h0.x; acc[k].y += v0 * h0.y;
                acc[k].z += v0 * h0.z; acc[k].w += v0 * h0.w;
            }
        }
        __syncthreads();
    }

    // ---- overflow records (normally zero) ----
    int novf = min(*ovf_cnt, OVF_MAX);
    int rowbase = b * ROWS_PER_BUCKET;
    for (int i = 0; i < novf; ++i) {
        int4 o = ovf[i];
        int ro = o.x - rowbase;
        if (ro >= 0 && ro < ROWS_PER_BUCKET && (ro & 15) == rg) {
            float4 h = H4[o.y * 16 + fc];
            float v = __int_as_float(o.z);
            int k = ro >> 4;
            acc[k].x += v * h.x; acc[k].y += v * h.y;
            acc[k].z += v * h.z; acc[k].w += v * h.w;
        }
    }

    // ---- coalesced writeback, exactly once ----
    #pragma unroll
    for (int k = 0; k < 8; ++k) {
        int row = rowbase + k * 16 + rg;
        if (row < N_NODES)
            reinterpret_cast<float4*>(out)[row * 16 + fc] = acc[k];
    }
}

extern "C" void kernel_launch(void* const* d_in, const int* in_sizes, int n_in,
                              void* d_out, int out_size, void* d_ws, size_t ws_size,
                              hipStream_t stream) {
    const float* H    = (const float*)d_in[0];
    const float* vals = (const float*)d_in[1];
    const int*   rows = (const int*)d_in[2];
    const int*   cols = (const int*)d_in[3];
    float* out = (float*)d_out;

    char* ws = (char*)d_ws;
    int2* rec     = (int2*)ws;                         // N_CELL*CAP*8B = 25.6 MB
    int*  cursor  = (int*)(rec + N_CELL * CAP);        // N_CELL*PAD = 400 KB
    int*  ovf_cnt = cursor + N_CELL * PAD;             // 16 ints
    int4* ovf     = (int4*)(ovf_cnt + 16);             // OVF_MAX*16B = 64 KB

    // zero cursors + overflow count (one memset; rec needs no init)
    hipMemsetAsync(cursor, 0, (N_CELL * PAD + 16) * sizeof(int), stream);

    scatter_kernel<<<2048, 256, 0, stream>>>(vals, rows, cols, cursor, rec, ovf, ovf_cnt);
    gather_kernel<<<N_BUCKET, 256, 0, stream>>>(H, rec, cursor, ovf, ovf_cnt, out);
}